// Round 5
// baseline (290.519 us; speedup 1.0000x reference)
//
#include <hip/hip_runtime.h>

#define NN 50000
#define NE 600000
#define DIM 128
#define NB_N 196   // ceil(50000/256)
#define NB_E 2344  // ceil(600000/256)
#define TILES 3125 // 50000/16
#define ROWW 136   // LDS row pitch in u16 (128 + 8 pad)
#define NEPAD (NE + 4 * NN + 64)  // rows padded to multiple of 4, min 4

typedef unsigned short u16;
typedef unsigned int u32;
typedef __attribute__((ext_vector_type(8))) short bf16x8;
typedef __attribute__((ext_vector_type(4))) float f32x4;

__device__ __forceinline__ u16 f2bf(float f) {
    u32 u = __builtin_bit_cast(u32, f);
    u32 r = (u + 0x7FFFu + ((u >> 16) & 1u)) >> 16;
    return (u16)r;
}
__device__ __forceinline__ float bflo(u32 w) { return __builtin_bit_cast(float, w << 16); }
__device__ __forceinline__ float bfhi(u32 w) { return __builtin_bit_cast(float, w & 0xffff0000u); }
__device__ __forceinline__ float i2f(int b) { return __builtin_bit_cast(float, b); }

// ---- CSR build (rows padded to multiple of 4, min 4; pad recs = {0,0}) -----

__global__ __launch_bounds__(256) void k_count(const int* __restrict__ ei,
                                               int* __restrict__ deg) {
    __shared__ int s64;
    if (threadIdx.x == 0) {
        int o = 0;
#pragma unroll
        for (int j = 0; j < 16; j++) o |= ei[2 * j + 1];  // int64 => high words 0
        s64 = (o == 0);
    }
    __syncthreads();
    int e = blockIdx.x * 256 + threadIdx.x;
    if (e >= NE) return;
    int d = s64 ? ei[2 * (NE + e)] : ei[NE + e];
    atomicAdd(&deg[d], 1);
}

__device__ __forceinline__ int pad4(int d) {
    int p = (d + 3) & ~3;
    return p < 4 ? 4 : p;
}

__global__ __launch_bounds__(256) void k_scanA(const int* __restrict__ deg,
                                               int* __restrict__ rp4,
                                               int* __restrict__ bsum) {
    __shared__ int buf[256];
    int t = threadIdx.x, i = blockIdx.x * 256 + t;
    int v = (i < NN) ? pad4(deg[i]) : 0;
    buf[t] = v;
    __syncthreads();
    for (int off = 1; off < 256; off <<= 1) {
        int x = (t >= off) ? buf[t - off] : 0;
        __syncthreads();
        buf[t] += x;
        __syncthreads();
    }
    if (i < NN) rp4[i] = buf[t] - v;
    if (t == 255) bsum[blockIdx.x] = buf[255];
}

__global__ __launch_bounds__(256) void k_scanB(int* __restrict__ bsum) {
    __shared__ int buf[256];
    int t = threadIdx.x;
    int v = (t < NB_N) ? bsum[t] : 0;
    buf[t] = v;
    __syncthreads();
    for (int off = 1; off < 256; off <<= 1) {
        int x = (t >= off) ? buf[t - off] : 0;
        __syncthreads();
        buf[t] += x;
        __syncthreads();
    }
    bsum[t] = buf[t] - v;  // t >= NB_N holds grand total
}

// finalize rp4, dinv; write zero pad records (so no giant memset needed)
__global__ __launch_bounds__(256) void k_scanC(const int* __restrict__ deg,
                                               int* __restrict__ rp4,
                                               const int* __restrict__ bsum,
                                               float* __restrict__ dinv,
                                               int2* __restrict__ recs) {
    int i = blockIdx.x * 256 + threadIdx.x;
    if (i < NN) {
        int rp = rp4[i] + bsum[i >> 8];
        rp4[i] = rp;
        int d = deg[i];
        dinv[i] = rsqrtf((float)(d + 1));  // +1 self loop
        int p = pad4(d);
        for (int j = d; j < p; j++) recs[rp + j] = make_int2(0, 0);
    }
    if (i == 0) rp4[NN] = bsum[255];
}

// recs[pos] = {src, bits(norm)}
__global__ __launch_bounds__(256) void k_fill(const int* __restrict__ ei,
                                              const int* __restrict__ rp4,
                                              int* __restrict__ cursor,
                                              const float* __restrict__ dinv,
                                              int2* __restrict__ recs) {
    __shared__ int s64;
    if (threadIdx.x == 0) {
        int o = 0;
#pragma unroll
        for (int j = 0; j < 16; j++) o |= ei[2 * j + 1];
        s64 = (o == 0);
    }
    __syncthreads();
    int e = blockIdx.x * 256 + threadIdx.x;
    if (e >= NE) return;
    int is64 = s64;
    int s = is64 ? ei[2 * e] : ei[e];
    int d = is64 ? ei[2 * (NE + e)] : ei[NE + e];
    int pos = rp4[d] + atomicAdd(&cursor[d], 1);
    int2 rc;
    rc.x = s;
    rc.y = __builtin_bit_cast(int, dinv[s] * dinv[d]);
    recs[pos] = rc;
}

// ---- weight cast: Wt[layer][n][k] = bf16(W[layer][k][n]) -------------------
__global__ __launch_bounds__(256) void k_wcast(const float* __restrict__ W0,
                                               const float* __restrict__ W1,
                                               const float* __restrict__ W2,
                                               u16* __restrict__ Wt) {
    int idx = blockIdx.x * 256 + threadIdx.x;  // < 3*16384
    int l = idx >> 14, rem = idx & 16383;
    int n = rem >> 7, k = rem & 127;
    const float* W = (l == 0) ? W0 : ((l == 1) ? W1 : W2);
    Wt[idx] = f2bf(W[k * 128 + n]);
}

// ---- layer-1 GEMM: hw[N,128] = bf16(x f32) @ W0 ----------------------------
__global__ __launch_bounds__(256) void k_gemm_f32(const float* __restrict__ x,
                                                  const u16* __restrict__ Wt,
                                                  u16* __restrict__ hwb) {
    int lane = threadIdx.x & 63;
    int tile = blockIdx.x * 4 + (threadIdx.x >> 6);
    if (tile >= TILES) return;
    int r = lane & 15, q = lane >> 4;

    bf16x8 Bf[8][4];
#pragma unroll
    for (int nt = 0; nt < 8; nt++)
#pragma unroll
        for (int kc = 0; kc < 4; kc++)
            Bf[nt][kc] = *(const bf16x8*)(Wt + ((nt * 16 + r) << 7) + kc * 32 + q * 8);

    long rowbase = (long)tile * 16;
    bf16x8 Af[4];
#pragma unroll
    for (int kc = 0; kc < 4; kc++) {
        const float4* p = (const float4*)(x + (rowbase + r) * 128 + kc * 32 + q * 8);
        float4 t0 = p[0], t1 = p[1];
        bf16x8 a;
        a[0] = (short)f2bf(t0.x); a[1] = (short)f2bf(t0.y);
        a[2] = (short)f2bf(t0.z); a[3] = (short)f2bf(t0.w);
        a[4] = (short)f2bf(t1.x); a[5] = (short)f2bf(t1.y);
        a[6] = (short)f2bf(t1.z); a[7] = (short)f2bf(t1.w);
        Af[kc] = a;
    }

#pragma unroll
    for (int nt = 0; nt < 8; nt++) {
        f32x4 acc = {0.f, 0.f, 0.f, 0.f};
#pragma unroll
        for (int kc = 0; kc < 4; kc++)
            acc = __builtin_amdgcn_mfma_f32_16x16x32_bf16(Af[kc], Bf[nt][kc], acc, 0, 0, 0);
#pragma unroll
        for (int i = 0; i < 4; i++)
            hwb[(rowbase + q * 4 + i) * 128 + nt * 16 + r] = f2bf(acc[i]);
    }
}

// ---- aggregation core: wave = 4 nodes (4 chains), ONE prologue.
// group g=lane>>4 handles edge (e+g) of EVERY chain; lane r=lane&15: feats 8r..
__device__ __forceinline__ void fma8(float* acc, uint4 u, float n) {
    acc[0] += n * bflo(u.x); acc[1] += n * bfhi(u.x);
    acc[2] += n * bflo(u.y); acc[3] += n * bfhi(u.y);
    acc[4] += n * bflo(u.z); acc[5] += n * bfhi(u.z);
    acc[6] += n * bflo(u.w); acc[7] += n * bfhi(u.w);
}

__device__ __forceinline__ void combine_bias_relu(float b0x, float b0y, float b0z,
                                                  float b0w, float b1x, float b1y,
                                                  float b1z, float b1w, float* acc) {
#pragma unroll
    for (int j = 0; j < 8; j++) {
        acc[j] += __shfl_xor(acc[j], 16, 64);
        acc[j] += __shfl_xor(acc[j], 32, 64);
    }
    acc[0] = fmaxf(acc[0] + b0x, 0.f); acc[1] = fmaxf(acc[1] + b0y, 0.f);
    acc[2] = fmaxf(acc[2] + b0z, 0.f); acc[3] = fmaxf(acc[3] + b0w, 0.f);
    acc[4] = fmaxf(acc[4] + b1x, 0.f); acc[5] = fmaxf(acc[5] + b1y, 0.f);
    acc[6] = fmaxf(acc[6] + b1z, 0.f); acc[7] = fmaxf(acc[7] + b1w, 0.f);
}

// A[c][8]: chain c's partial (per lane). After this, still needs combine.
__device__ __forceinline__ void agg_quad(const u16* __restrict__ hw,
                                         const int* __restrict__ rp4,
                                         const int2* __restrict__ recs,
                                         const float* __restrict__ dinv,
                                         int vbase, int g, int r,
                                         float A[4][8]) {
    int4 rlo = *(const int4*)(rp4 + vbase);  // vbase % 4 == 0 -> aligned
    int rhi = rp4[vbase + 4];
    int s0 = rlo.x, s1 = rlo.y, s2 = rlo.z, s3 = rlo.w;
    int l0 = rlo.y - rlo.x, l1 = rlo.z - rlo.y, l2 = rlo.w - rlo.z, l3 = rhi - rlo.w;

    // self row: group g loads chain g's row (issued before rec deps resolve)
    uint4 sv = *(const uint4*)(hw + (size_t)(vbase + g) * DIM + r * 8);
    float4 dv4 = *(const float4*)(dinv + vbase);
    float dvg = (g == 0) ? dv4.x : (g == 1) ? dv4.y : (g == 2) ? dv4.z : dv4.w;
    float sc = dvg * dvg;

    // first record of each chain (l >= 4 guaranteed)
    int2 q0 = recs[s0 + g], q1 = recs[s1 + g], q2 = recs[s2 + g], q3 = recs[s3 + g];

#pragma unroll
    for (int c = 0; c < 4; c++) {
        float s = (g == c) ? sc : 0.f;  // self term counted once (in group c)
        A[c][0] = s * bflo(sv.x); A[c][1] = s * bfhi(sv.x);
        A[c][2] = s * bflo(sv.y); A[c][3] = s * bfhi(sv.y);
        A[c][4] = s * bflo(sv.z); A[c][5] = s * bfhi(sv.z);
        A[c][6] = s * bflo(sv.w); A[c][7] = s * bfhi(sv.w);
    }

    int nit = max(max(l0, l1), max(l2, l3)) >> 2;
    for (int it = 0; it < nit; ++it) {
        uint4 u0 = *(const uint4*)(hw + (size_t)(u32)q0.x * DIM + r * 8);
        uint4 u1 = *(const uint4*)(hw + (size_t)(u32)q1.x * DIM + r * 8);
        uint4 u2 = *(const uint4*)(hw + (size_t)(u32)q2.x * DIM + r * 8);
        uint4 u3 = *(const uint4*)(hw + (size_t)(u32)q3.x * DIM + r * 8);
        int nx = 4 * (it + 1);
        int2 p0 = recs[s0 + min(nx, l0 - 4) + g];
        int2 p1 = recs[s1 + min(nx, l1 - 4) + g];
        int2 p2 = recs[s2 + min(nx, l2 - 4) + g];
        int2 p3 = recs[s3 + min(nx, l3 - 4) + g];
        int cur = 4 * it;  // clamped re-reads of last block: zero the norm
        float n0 = (cur < l0) ? i2f(q0.y) : 0.f;
        float n1 = (cur < l1) ? i2f(q1.y) : 0.f;
        float n2 = (cur < l2) ? i2f(q2.y) : 0.f;
        float n3 = (cur < l3) ? i2f(q3.y) : 0.f;
        fma8(A[0], u0, n0);
        fma8(A[1], u1, n1);
        fma8(A[2], u2, n2);
        fma8(A[3], u3, n3);
        q0 = p0; q1 = p1; q2 = p2; q3 = p3;
    }
}

// ---- fused: h = relu(agg(hw_in)+b) -> LDS tile -> hw_out = h @ W -----------
// block = 16 nodes, 4 waves; wave w aggregates nodes w*4..w*4+3 in parallel
__global__ __launch_bounds__(256) void k_agg_gemm(const u16* __restrict__ hw_in,
                                                  const int* __restrict__ rp4,
                                                  const int2* __restrict__ recs,
                                                  const float* __restrict__ dinv,
                                                  const float* __restrict__ bias,
                                                  const u16* __restrict__ Wt,
                                                  u16* __restrict__ hw_out) {
    __shared__ u16 sm[16 * ROWW];
    int lane = threadIdx.x & 63;
    int w = threadIdx.x >> 6;
    int g = lane >> 4, r = lane & 15;
    int base = blockIdx.x * 16;
    int vbase = base + w * 4;

    float4 b0 = ((const float4*)bias)[2 * r];
    float4 b1 = ((const float4*)bias)[2 * r + 1];

    float A[4][8];
    agg_quad(hw_in, rp4, recs, dinv, vbase, g, r, A);
#pragma unroll
    for (int c = 0; c < 4; c++) {
        combine_bias_relu(b0.x, b0.y, b0.z, b0.w, b1.x, b1.y, b1.z, b1.w, A[c]);
        if (g == c) {  // group c writes chain c's row (4 parallel LDS writes)
            uint4 pk;
            pk.x = (u32)f2bf(A[c][0]) | ((u32)f2bf(A[c][1]) << 16);
            pk.y = (u32)f2bf(A[c][2]) | ((u32)f2bf(A[c][3]) << 16);
            pk.z = (u32)f2bf(A[c][4]) | ((u32)f2bf(A[c][5]) << 16);
            pk.w = (u32)f2bf(A[c][6]) | ((u32)f2bf(A[c][7]) << 16);
            *(uint4*)(sm + (w * 4 + c) * ROWW + r * 8) = pk;
        }
    }
    __syncthreads();
    // GEMM: 16x128 LDS tile @ 128x128 W; wave w does n-tiles {2w, 2w+1}
    int q = lane >> 4;
    bf16x8 Af[4];
#pragma unroll
    for (int kc = 0; kc < 4; kc++)
        Af[kc] = *(const bf16x8*)(sm + r * ROWW + kc * 32 + q * 8);
#pragma unroll
    for (int t = 0; t < 2; t++) {
        int nt = w * 2 + t;
        f32x4 acc = {0.f, 0.f, 0.f, 0.f};
#pragma unroll
        for (int kc = 0; kc < 4; kc++) {
            bf16x8 Bf = *(const bf16x8*)(Wt + ((nt * 16 + r) << 7) + kc * 32 + q * 8);
            acc = __builtin_amdgcn_mfma_f32_16x16x32_bf16(Af[kc], Bf, acc, 0, 0, 0);
        }
#pragma unroll
        for (int i = 0; i < 4; i++)
            hw_out[(size_t)(base + q * 4 + i) * DIM + nt * 16 + r] = f2bf(acc[i]);
    }
}

// ---- final layer: relu(agg+b) -> f32 out, 4 nodes per wave -----------------
__global__ __launch_bounds__(256) void k_agg_out(const u16* __restrict__ hw_in,
                                                 const int* __restrict__ rp4,
                                                 const int2* __restrict__ recs,
                                                 const float* __restrict__ dinv,
                                                 const float* __restrict__ bias,
                                                 float* __restrict__ out) {
    int lane = threadIdx.x & 63;
    int w = threadIdx.x >> 6;
    int g = lane >> 4, r = lane & 15;
    int vbase = blockIdx.x * 16 + w * 4;  // grid 3125 exact

    float4 b0 = ((const float4*)bias)[2 * r];
    float4 b1 = ((const float4*)bias)[2 * r + 1];

    float A[4][8];
    agg_quad(hw_in, rp4, recs, dinv, vbase, g, r, A);
#pragma unroll
    for (int c = 0; c < 4; c++) {
        combine_bias_relu(b0.x, b0.y, b0.z, b0.w, b1.x, b1.y, b1.z, b1.w, A[c]);
        if (g == c) {
            float4* p = (float4*)(out + (size_t)(vbase + c) * DIM + r * 8);
            p[0] = make_float4(A[c][0], A[c][1], A[c][2], A[c][3]);
            p[1] = make_float4(A[c][4], A[c][5], A[c][6], A[c][7]);
        }
    }
}

// ---- launch ----------------------------------------------------------------

extern "C" void kernel_launch(void* const* d_in, const int* in_sizes, int n_in,
                              void* d_out, int out_size, void* d_ws, size_t ws_size,
                              hipStream_t stream) {
    const float* x = (const float*)d_in[0];
    const int* ei = (const int*)d_in[1];
    const float* W0 = (const float*)d_in[2];
    const float* b0 = (const float*)d_in[3];
    const float* W1 = (const float*)d_in[4];
    const float* b1 = (const float*)d_in[5];
    const float* W2 = (const float*)d_in[6];
    const float* b2 = (const float*)d_in[7];

    char* ws = (char*)d_ws;
    size_t off = 0;
    auto alloc = [&](size_t bytes) -> void* {
        void* p = ws + off;
        off += (bytes + 511) & ~(size_t)511;
        return p;
    };
    int* deg = (int*)alloc(NN * 4);      // zeroed
    int* cursor = (int*)alloc(NN * 4);   // zeroed
    size_t zbytes = off;
    int2* recs = (int2*)alloc((size_t)NEPAD * 8);  // pads written by k_scanC
    float* dinv = (float*)alloc(NN * 4);
    int* rp4 = (int*)alloc((NN + 1) * 4);
    int* bsum = (int*)alloc(256 * 4);
    u16* Wt = (u16*)alloc(3 * 128 * 128 * 2);
    u16* hwA = (u16*)alloc((size_t)NN * DIM * 2);
    u16* hwB = (u16*)alloc((size_t)NN * DIM * 2);

    hipMemsetAsync(ws, 0, zbytes, stream);
    k_count<<<NB_E, 256, 0, stream>>>(ei, deg);
    k_scanA<<<NB_N, 256, 0, stream>>>(deg, rp4, bsum);
    k_scanB<<<1, 256, 0, stream>>>(bsum);
    k_scanC<<<NB_N, 256, 0, stream>>>(deg, rp4, bsum, dinv, recs);
    k_fill<<<NB_E, 256, 0, stream>>>(ei, rp4, cursor, dinv, recs);
    k_wcast<<<192, 256, 0, stream>>>(W0, W1, W2, Wt);

    k_gemm_f32<<<(TILES + 3) / 4, 256, 0, stream>>>(x, Wt, hwA);                 // hw1
    k_agg_gemm<<<TILES, 256, 0, stream>>>(hwA, rp4, recs, dinv, b0,
                                          Wt + 16384, hwB);                      // hw2
    k_agg_gemm<<<TILES, 256, 0, stream>>>(hwB, rp4, recs, dinv, b1,
                                          Wt + 32768, hwA);                      // hw3
    k_agg_out<<<TILES, 256, 0, stream>>>(hwA, rp4, recs, dinv, b2,
                                         (float*)d_out);
}